// Round 5
// baseline (195.988 us; speedup 1.0000x reference)
//
#include <hip/hip_runtime.h>
#include <hip/hip_bf16.h>
#include <stdint.h>

using bf16 = __hip_bfloat16;
typedef __attribute__((ext_vector_type(8))) short bf16x8;   // 8 bf16 raw bits (4 VGPRs)
typedef __attribute__((ext_vector_type(4))) float f32x4;

__device__ __forceinline__ void async_load16(const void* g, void* l) {
    __builtin_amdgcn_global_load_lds(
        (__attribute__((address_space(1))) const void*)g,
        (__attribute__((address_space(3))) void*)l,
        16, 0, 0);
}

// ---------------- converts ----------------
__device__ __forceinline__ void cvt_block_2048(const float* __restrict__ src,
                                               bf16* __restrict__ dst, int relblk) {
    int i = (relblk * 256 + (int)threadIdx.x) * 8;
    float4 f0 = *(const float4*)(src + i);
    float4 f1 = *(const float4*)(src + i + 4);
    union { bf16 h[8]; uint4 u; } o;
    o.h[0] = __float2bfloat16(f0.x); o.h[1] = __float2bfloat16(f0.y);
    o.h[2] = __float2bfloat16(f0.z); o.h[3] = __float2bfloat16(f0.w);
    o.h[4] = __float2bfloat16(f1.x); o.h[5] = __float2bfloat16(f1.y);
    o.h[6] = __float2bfloat16(f1.z); o.h[7] = __float2bfloat16(f1.w);
    *(uint4*)(dst + i) = o.u;
}

__global__ __launch_bounds__(256) void prep_w(
    const float* __restrict__ w1, bf16* __restrict__ w1b,
    const float* __restrict__ wup, bf16* __restrict__ wub,
    const float* __restrict__ wd, bf16* __restrict__ wdt,
    const float* __restrict__ w2, bf16* __restrict__ w2t) {
    __shared__ bf16 sh[32][33];
    int b = blockIdx.x;
    if (b < 128)       { cvt_block_2048(w1, w1b, b); return; }
    if (b < 640)       { cvt_block_2048(wup, wub, b - 128); return; }
    const float* src; bf16* dst; int R, C, tile, ntx;
    if (b < 1664) { src = wd; dst = wdt; R = 512; C = 2048; tile = b - 640; ntx = 64; }
    else          { src = w2; dst = w2t; R = 512; C = 512;  tile = b - 1664; ntx = 16; }
    const int bx = (tile % ntx) * 32, by = (tile / ntx) * 32;
    const int lx = threadIdx.x & 31;
    const int ly4 = ((int)threadIdx.x >> 5) * 4;
#pragma unroll
    for (int r = 0; r < 4; ++r)
        sh[ly4 + r][lx] = __float2bfloat16(src[(size_t)(by + ly4 + r) * C + bx + lx]);
    __syncthreads();
#pragma unroll
    for (int r = 0; r < 4; ++r)
        dst[(size_t)(bx + ly4 + r) * R + by + lx] = sh[lx][ly4 + r];
}

// ---------------- staging: global -> LDS (swizzled, linear dest) ----------------
// BK=64: chunk = 8 rows x 64 cols (1KB); unit(r,c8) = r*8 + (c8 ^ (r&7)).
// <=2-way aliasing per 16-lane ds_read_b128 phase (free, m136).
template<int BN, int NW>
__device__ __forceinline__ void stage_tiles(
    const bf16* __restrict__ A, const bf16* __restrict__ B,
    size_t bm, size_t bn, int K, int k0,
    bf16* __restrict__ As, bf16* __restrict__ Bs, int wave, int lane)
{
    const int srow = lane >> 3;
    const int scol = (lane & 7) ^ srow;
    constexpr int NCH = (128 + BN) / 8;
#pragma unroll
    for (int c = 0; c < NCH / NW; ++c) {
        const int cc = wave + c * NW;
        if (cc < 16) {
            const int rb = cc * 8;
            async_load16(A + (bm + rb + srow) * (size_t)K + k0 + scol * 8,
                         &As[rb * 64]);
        } else {
            const int rb = (cc - 16) * 8;
            async_load16(B + (bn + rb + srow) * (size_t)K + k0 + scol * 8,
                         &Bs[rb * 64]);
        }
    }
}

// ---------------- GEMM core (bf16 A and B): C[MxN] = A[MxK] * B[NxK]^T ------
// BM=128, BK=64, NW waves. Wave grid 2 x (NW/2); each wave owns a 64x32
// sub-tile -> acc[4][2]. Double-buffered LDS, prefetch-next-tile.
// EPI==1 (NW=8, KT=512): one Res float4 load per K-iter (HBM read overlaps the
// K-loop); epilogue write-only Cf = Res + s*acc via wave-private LDS transpose.
template<int BN, int EPI, int KT, int NW>
__device__ __forceinline__ void gemm_core(
    const bf16* __restrict__ A, const bf16* __restrict__ B,
    bf16* __restrict__ Cb, float* __restrict__ Cf,
    const float* __restrict__ Res, const float* __restrict__ sp,
    int N, int K, int bxi, int byi, bf16* smem)
{
    constexpr int BM = 128;
    constexpr int BK = 64;
    constexpr int WN = NW / 2;          // waves along N
    constexpr int NJ = 2;               // 2 x 16 cols per wave
    constexpr int BUF = (BM + BN) * BK; // bf16 elems per LDS buffer
    static_assert(BN == WN * 32, "wave tile is 64x32");
    static_assert(NW == 4 || NW == 8, "NW");
    static_assert(EPI == 0 || (NW == 8 && KT == 512), "EPI path: 8 waves, KT=512");

    const int tid  = threadIdx.x;
    const int wave = tid >> 6;
    const int lane = tid & 63;
    const int wm = wave / WN, wn = wave % WN;
    const size_t bm = (size_t)bxi * BM;
    const size_t bn = (size_t)byi * BN;

    f32x4 acc[4][NJ];
#pragma unroll
    for (int i = 0; i < 4; ++i)
#pragma unroll
        for (int j = 0; j < NJ; ++j)
            acc[i][j] = (f32x4){0.f, 0.f, 0.f, 0.f};

    float4 res_pre[EPI ? 8 : 1];
    const int r16 = lane >> 3;        // res/epilogue row-in-8
    const int cbb = (lane & 7) * 4;   // res/epilogue col base (float4)

    auto compute_tile = [&](const bf16* Ap, const bf16* Bp) {
#pragma unroll
        for (int kk = 0; kk < 2; ++kk) {
            const int c8 = kk * 4 + (lane >> 4);
            bf16x8 af[4], bfr[NJ];
#pragma unroll
            for (int i = 0; i < 4; ++i) {
                const int r = wm * 64 + i * 16 + (lane & 15);
                af[i] = *(const bf16x8*)&Ap[(size_t)(r * 8 + (c8 ^ (r & 7))) * 8];
            }
#pragma unroll
            for (int j = 0; j < NJ; ++j) {
                const int r = wn * 32 + j * 16 + (lane & 15);
                bfr[j] = *(const bf16x8*)&Bp[(size_t)(r * 8 + (c8 ^ (r & 7))) * 8];
            }
#pragma unroll
            for (int i = 0; i < 4; ++i)
#pragma unroll
                for (int j = 0; j < NJ; ++j)
                    acc[i][j] = __builtin_amdgcn_mfma_f32_16x16x32_bf16(af[i], bfr[j], acc[i][j], 0, 0, 0);
        }
    };

    // prologue: fill buffer 0, drain
    stage_tiles<BN, NW>(A, B, bm, bn, K, 0, smem, smem + BM * BK, wave, lane);
    __syncthreads();

    if constexpr (KT > 0) {
#pragma unroll
        for (int it = 0; it < KT / BK; ++it) {
            const int cur = it & 1;
            if (it + 1 < KT / BK) {
                bf16* nb = smem + (cur ^ 1) * BUF;
                stage_tiles<BN, NW>(A, B, bm, bn, KT, (it + 1) * BK, nb, nb + BM * BK, wave, lane);
            }
            if constexpr (EPI) {
                // one Res float4 per iteration -> HBM read overlaps K-loop
                const int i = it >> 1, rh = it & 1;
                size_t row = bm + wm * 64 + i * 16 + rh * 8 + r16;
                size_t col = bn + wn * 32 + cbb;
                res_pre[it] = *(const float4*)&Res[row * (size_t)N + col];
            }
            const bf16* Ap = smem + cur * BUF;
            compute_tile(Ap, Ap + BM * BK);
            __syncthreads();   // drains prefetch + this iter's res load
        }
    } else {
        int cur = 0;
        for (int k0 = 0; k0 < K; k0 += BK) {
            if (k0 + BK < K) {
                bf16* nb = smem + (cur ^ 1) * BUF;
                stage_tiles<BN, NW>(A, B, bm, bn, K, k0 + BK, nb, nb + BM * BK, wave, lane);
            }
            const bf16* Ap = smem + cur * BUF;
            compute_tile(Ap, Ap + BM * BK);
            __syncthreads();
            cur ^= 1;
        }
    }

    // C/D layout: col = lane&15, row = (lane>>4)*4 + reg
    const int col_l = lane & 15;
    const int row_l = (lane >> 4) * 4;
    if (EPI == 0) {
#pragma unroll
        for (int i = 0; i < 4; ++i)
#pragma unroll
            for (int j = 0; j < NJ; ++j)
#pragma unroll
                for (int r = 0; r < 4; ++r) {
                    size_t row = bm + wm * 64 + i * 16 + row_l + r;
                    size_t col = bn + wn * 32 + j * 16 + col_l;
                    Cb[row * (size_t)N + col] = __float2bfloat16(acc[i][j][r]);
                }
    } else {
        // wave-private 16x32 fp32 slice in LDS (stride 36 breaks bank aliasing);
        // no barriers: producer/consumer lanes are in the same wave.
        const float s = *sp;
        float* lds_f = (float*)smem + wave * (16 * 36);
#pragma unroll
        for (int i = 0; i < 4; ++i) {
#pragma unroll
            for (int j = 0; j < NJ; ++j)
#pragma unroll
                for (int r = 0; r < 4; ++r)
                    lds_f[(row_l + r) * 36 + j * 16 + col_l] = acc[i][j][r];
#pragma unroll
            for (int rh = 0; rh < 2; ++rh) {
                const int rr = rh * 8 + r16;
                float4 v = *(float4*)&lds_f[rr * 36 + cbb];
                size_t row = bm + wm * 64 + i * 16 + rr;
                size_t col = bn + wn * 32 + cbb;
                size_t idx = row * (size_t)N + col;
                float4 rv = res_pre[i * 2 + rh];
                float4 o;
                o.x = rv.x + s * v.x; o.y = rv.y + s * v.y;
                o.z = rv.z + s * v.z; o.w = rv.w + s * v.w;
                *(float4*)&Cf[idx] = o;
            }
        }
    }
}

// XCD-aware swizzle (T1): blocks with equal (flat & 7) land on one XCD and get
// a contiguous swz range -> all N-tiles of an M-slab share that XCD's L2.
template<int BN, int EPI, int KT, int NW>
__global__ __launch_bounds__(NW * 64) void gemm_bf16(
    const bf16* __restrict__ A, const bf16* __restrict__ B,
    bf16* __restrict__ Cb, float* __restrict__ Cf,
    const float* __restrict__ Res, const float* __restrict__ sp, int N, int K) {
    __shared__ __align__(16) bf16 smem[(128 + BN) * 64 * 2];
    const int nx = gridDim.x;
    const int flat = blockIdx.y * nx + blockIdx.x;
    const int chunk = (nx * gridDim.y) >> 3;
    const int swz = (flat & 7) * chunk + (flat >> 3);
    gemm_core<BN, EPI, KT, NW>(A, B, Cb, Cf, Res, sp, N, K,
                               swz / nx, swz % nx, smem);
}

// ---------------- x_gemm: x = NT(hs_fp32, R_bf16), convert fused ------------
// M=8192, N=512, K=2048. Block 128x64, 4 waves (64x32 wave tiles), dbuf 48 KB.
// Grid (8,64) = 512 blocks -> 2 blocks/CU, 8 waves/CU (2/SIMD): independent
// blocks overlap each other's barrier/staging stalls (round-4's 256-block
// 1-wave/SIMD version was latency-bound at Occupancy 9%).
// A (hs, fp32) is reg-staged: global float4 x2 -> cvt -> ds_write_b128 into the
// XOR-swizzled layout (T14: loads issued before compute, writes after).
// B via global_load_lds. Kills the separate hs->bf16 pass (96 MiB).
__global__ __launch_bounds__(256) void x_gemm(
    const float* __restrict__ A32, const bf16* __restrict__ B,
    bf16* __restrict__ Cb, int N, int K)
{
    constexpr int BM = 128, BN = 64, BK = 64;
    constexpr int BUF = (BM + BN) * BK;
    __shared__ __align__(16) bf16 smem[BUF * 2];

    const int nx = gridDim.x;                       // 8 N-tiles
    const int flat = blockIdx.y * nx + blockIdx.x;
    const int chunk = (nx * gridDim.y) >> 3;
    const int swz = (flat & 7) * chunk + (flat >> 3);
    const int bxi = swz / nx, byi = swz % nx;
    const size_t bm = (size_t)bxi * BM;
    const size_t bn = (size_t)byi * BN;

    const int tid = threadIdx.x, wave = tid >> 6, lane = tid & 63;
    const int wm = wave >> 1, wn = wave & 1;

    f32x4 acc[4][2];
#pragma unroll
    for (int i = 0; i < 4; ++i)
#pragma unroll
        for (int j = 0; j < 2; ++j)
            acc[i][j] = (f32x4){0.f, 0.f, 0.f, 0.f};

    float4 av[4][2];   // in-flight A fp32 (unit = tid + u*256: r=unit>>3, c8=unit&7)

    auto loadA = [&](int k0) {
#pragma unroll
        for (int u = 0; u < 4; ++u) {
            const int unit = tid + u * 256;
            const int r = unit >> 3, c8 = unit & 7;
            const float* g = A32 + (bm + r) * (size_t)K + k0 + c8 * 8;
            av[u][0] = *(const float4*)g;
            av[u][1] = *(const float4*)(g + 4);
        }
    };
    auto writeA = [&](bf16* As) {
#pragma unroll
        for (int u = 0; u < 4; ++u) {
            const int unit = tid + u * 256;
            const int r = unit >> 3, c8 = unit & 7;
            const int su = (r >> 3) * 64 + (r & 7) * 8 + (c8 ^ (r & 7));
            union { bf16 h[8]; uint4 q; } o;
            o.h[0] = __float2bfloat16(av[u][0].x); o.h[1] = __float2bfloat16(av[u][0].y);
            o.h[2] = __float2bfloat16(av[u][0].z); o.h[3] = __float2bfloat16(av[u][0].w);
            o.h[4] = __float2bfloat16(av[u][1].x); o.h[5] = __float2bfloat16(av[u][1].y);
            o.h[6] = __float2bfloat16(av[u][1].z); o.h[7] = __float2bfloat16(av[u][1].w);
            *(uint4*)&As[(size_t)su * 8] = o.q;
        }
    };
    auto stageB = [&](bf16* Bs, int k0) {
        const int srow = lane >> 3;
        const int scol = (lane & 7) ^ srow;
#pragma unroll
        for (int c = 0; c < 2; ++c) {
            const int rb = (wave + c * 4) * 8;
            async_load16(B + (bn + rb + srow) * (size_t)K + k0 + scol * 8,
                         &Bs[rb * 64]);
        }
    };
    auto compute = [&](const bf16* Ap, const bf16* Bp) {
#pragma unroll
        for (int kk = 0; kk < 2; ++kk) {
            const int c8 = kk * 4 + (lane >> 4);
            bf16x8 af[4], bfr[2];
#pragma unroll
            for (int i = 0; i < 4; ++i) {
                const int r = wm * 64 + i * 16 + (lane & 15);
                af[i] = *(const bf16x8*)&Ap[(size_t)(r * 8 + (c8 ^ (r & 7))) * 8];
            }
#pragma unroll
            for (int j = 0; j < 2; ++j) {
                const int r = wn * 32 + j * 16 + (lane & 15);
                bfr[j] = *(const bf16x8*)&Bp[(size_t)(r * 8 + (c8 ^ (r & 7))) * 8];
            }
#pragma unroll
            for (int i = 0; i < 4; ++i)
#pragma unroll
                for (int j = 0; j < 2; ++j)
                    acc[i][j] = __builtin_amdgcn_mfma_f32_16x16x32_bf16(af[i], bfr[j], acc[i][j], 0, 0, 0);
        }
    };

    // prologue
    loadA(0);
    writeA(smem);
    stageB(smem + BM * BK, 0);
    __syncthreads();

    int cur = 0;
    for (int k0 = 0; k0 < K; k0 += BK) {
        const bool more = (k0 + BK) < K;
        if (more) {
            loadA(k0 + BK);                                  // issue early (T14)
            stageB(smem + (cur ^ 1) * BUF + BM * BK, k0 + BK);
        }
        compute(smem + cur * BUF, smem + cur * BUF + BM * BK);
        if (more) writeA(smem + (cur ^ 1) * BUF);            // write late
        __syncthreads();
        cur ^= 1;
    }

    const int col_l = lane & 15;
    const int row_l = (lane >> 4) * 4;
#pragma unroll
    for (int i = 0; i < 4; ++i)
#pragma unroll
        for (int j = 0; j < 2; ++j)
#pragma unroll
            for (int r = 0; r < 4; ++r) {
                size_t row = bm + wm * 64 + i * 16 + row_l + r;
                size_t col = bn + wn * 32 + j * 16 + col_l;
                Cb[row * (size_t)N + col] = __float2bfloat16(acc[i][j][r]);
            }
}

// R = W1*Wd, U = Wup*W2 — 256 blocks (hs convert fused into x_gemm).
__global__ __launch_bounds__(256) void ru(
    const bf16* __restrict__ A0, const bf16* __restrict__ B0, bf16* __restrict__ C0,
    const bf16* __restrict__ A1, const bf16* __restrict__ B1, bf16* __restrict__ C1) {
    __shared__ __align__(16) bf16 smem[(128 + 64) * 64 * 2];
    int b = blockIdx.x;
    if (b < 128)        // R = NT(W1, Wd^T): M=512,N=2048,K=512, tiles 4x32
        gemm_core<64, 0, 0, 4>(A0, B0, C0, nullptr, nullptr, nullptr, 2048, 512,
                               b / 32, b % 32, smem);
    else {              // U = NT(Wup, W2^T): M=2048,N=512,K=512, tiles 16x8
        int bb = b - 128;
        gemm_core<64, 0, 0, 4>(A1, B1, C1, nullptr, nullptr, nullptr, 512, 512,
                               bb / 8, bb % 8, smem);
    }
}

extern "C" void kernel_launch(void* const* d_in, const int* in_sizes, int n_in,
                              void* d_out, int out_size, void* d_ws, size_t ws_size,
                              hipStream_t stream) {
    // setup_inputs() order: hidden_states, w_down, w_up, w1, w2, residual_scale
    const float* hs     = (const float*)d_in[0];   // [8192, 2048]
    const float* w_down = (const float*)d_in[1];   // [512, 2048]
    const float* w_up   = (const float*)d_in[2];   // [2048, 512]
    const float* w1     = (const float*)d_in[3];   // [512, 512]
    const float* w2     = (const float*)d_in[4];   // [512, 512]
    const float* rs     = (const float*)d_in[5];   // scalar on device

    char* ws = (char*)d_ws;
    bf16* x_b   = (bf16*)(ws + 33554432);   //  8,388,608  x [8192x512]
    bf16* w1_b  = (bf16*)(ws + 41943040);   //    524,288  W1 [512x512]
    bf16* wu_b  = (bf16*)(ws + 42467328);   //  2,097,152  Wup [2048x512]
    bf16* wdt_b = (bf16*)(ws + 44564480);   //  2,097,152  Wd^T [2048x512]
    bf16* w2t_b = (bf16*)(ws + 46661632);   //    524,288  W2^T [512x512]
    bf16* Rm    = (bf16*)(ws + 47185920);   //  2,097,152  R = W1*Wd [512x2048]
    bf16* Um    = (bf16*)(ws + 49283072);   //  2,097,152  U = Wup*W2 [2048x512]

    // 1) weight converts/transposes (short critical-path stage)
    prep_w<<<dim3(1920), dim3(256), 0, stream>>>(w1, w1_b, w_up, wu_b, w_down, wdt_b, w2, w2t_b);
    // 2) R,U GEMMs only (hs convert fused into stage 3)
    ru<<<dim3(256), dim3(256), 0, stream>>>(w1_b, wdt_b, Rm, wu_b, w2t_b, Um);
    // 3) x = NT(hs, R) with fused fp32->bf16 A-staging. 128x64 block, 4 waves,
    //    dbuf 48 KB. grid (8,64) = 512 blocks (2/CU, 2 waves/SIMD), XCD-swizzled.
    x_gemm<<<dim3(8, 64), dim3(256), 0, stream>>>(hs, Rm, x_b, 512, 2048);
    // 4) out = res + s*NT(x, U): M=8192,N=2048,K=512 (KT=512, 8 iters).
    //    128x128 tiles, 8 waves, dbuf, grid (16,64), XCD-swizzled,
    //    1 Res float4 per K-iter overlapped.
    gemm_bf16<128, 1, 512, 8><<<dim3(16, 64), dim3(512), 0, stream>>>(x_b, Um, nullptr, (float*)d_out,
                                                                      hs, rs, 2048, 512);
}

// Round 6
// 181.978 us; speedup vs baseline: 1.0770x; 1.0770x over previous
//
#include <hip/hip_runtime.h>
#include <hip/hip_bf16.h>
#include <stdint.h>

using bf16 = __hip_bfloat16;
typedef __attribute__((ext_vector_type(8))) short bf16x8;   // 8 bf16 raw bits (4 VGPRs)
typedef __attribute__((ext_vector_type(4))) float f32x4;

__device__ __forceinline__ void async_load16(const void* g, void* l) {
    __builtin_amdgcn_global_load_lds(
        (__attribute__((address_space(1))) const void*)g,
        (__attribute__((address_space(3))) void*)l,
        16, 0, 0);
}

// ---------------- converts ----------------
__device__ __forceinline__ void cvt_block_2048(const float* __restrict__ src,
                                               bf16* __restrict__ dst, int relblk) {
    int i = (relblk * 256 + (int)threadIdx.x) * 8;
    float4 f0 = *(const float4*)(src + i);
    float4 f1 = *(const float4*)(src + i + 4);
    union { bf16 h[8]; uint4 u; } o;
    o.h[0] = __float2bfloat16(f0.x); o.h[1] = __float2bfloat16(f0.y);
    o.h[2] = __float2bfloat16(f0.z); o.h[3] = __float2bfloat16(f0.w);
    o.h[4] = __float2bfloat16(f1.x); o.h[5] = __float2bfloat16(f1.y);
    o.h[6] = __float2bfloat16(f1.z); o.h[7] = __float2bfloat16(f1.w);
    *(uint4*)(dst + i) = o.u;
}

__global__ __launch_bounds__(256) void prep_w(
    const float* __restrict__ w1, bf16* __restrict__ w1b,
    const float* __restrict__ wup, bf16* __restrict__ wub,
    const float* __restrict__ wd, bf16* __restrict__ wdt,
    const float* __restrict__ w2, bf16* __restrict__ w2t) {
    __shared__ bf16 sh[32][33];
    int b = blockIdx.x;
    if (b < 128)       { cvt_block_2048(w1, w1b, b); return; }
    if (b < 640)       { cvt_block_2048(wup, wub, b - 128); return; }
    const float* src; bf16* dst; int R, C, tile, ntx;
    if (b < 1664) { src = wd; dst = wdt; R = 512; C = 2048; tile = b - 640; ntx = 64; }
    else          { src = w2; dst = w2t; R = 512; C = 512;  tile = b - 1664; ntx = 16; }
    const int bx = (tile % ntx) * 32, by = (tile / ntx) * 32;
    const int lx = threadIdx.x & 31;
    const int ly4 = ((int)threadIdx.x >> 5) * 4;
#pragma unroll
    for (int r = 0; r < 4; ++r)
        sh[ly4 + r][lx] = __float2bfloat16(src[(size_t)(by + ly4 + r) * C + bx + lx]);
    __syncthreads();
#pragma unroll
    for (int r = 0; r < 4; ++r)
        dst[(size_t)(bx + ly4 + r) * R + by + lx] = sh[lx][ly4 + r];
}

// ---------------- staging: global -> LDS (swizzled, linear dest) ----------------
// BK=64: chunk = 8 rows x 64 cols (1KB); unit(r,c8) = r*8 + (c8 ^ (r&7)).
// <=2-way aliasing per 16-lane ds_read_b128 phase (free, m136).
template<int BN, int NW>
__device__ __forceinline__ void stage_tiles(
    const bf16* __restrict__ A, const bf16* __restrict__ B,
    size_t bm, size_t bn, int K, int k0,
    bf16* __restrict__ As, bf16* __restrict__ Bs, int wave, int lane)
{
    const int srow = lane >> 3;
    const int scol = (lane & 7) ^ srow;
    constexpr int NCH = (128 + BN) / 8;
#pragma unroll
    for (int c = 0; c < NCH / NW; ++c) {
        const int cc = wave + c * NW;
        if (cc < 16) {
            const int rb = cc * 8;
            async_load16(A + (bm + rb + srow) * (size_t)K + k0 + scol * 8,
                         &As[rb * 64]);
        } else {
            const int rb = (cc - 16) * 8;
            async_load16(B + (bn + rb + srow) * (size_t)K + k0 + scol * 8,
                         &Bs[rb * 64]);
        }
    }
}

// ---------------- GEMM core (bf16 A and B): C[MxN] = A[MxK] * B[NxK]^T ------
// BM=128, BK=64, NW waves. Wave grid 2 x (NW/2); each wave owns a 64x32
// sub-tile -> acc[4][2]. Double-buffered LDS, prefetch-next-tile.
// EPI==1 (NW=8, KT=512): one Res float4 load per K-iter (HBM read overlaps the
// K-loop); epilogue write-only Cf = Res + s*acc via wave-private LDS transpose.
template<int BN, int EPI, int KT, int NW>
__device__ __forceinline__ void gemm_core(
    const bf16* __restrict__ A, const bf16* __restrict__ B,
    bf16* __restrict__ Cb, float* __restrict__ Cf,
    const float* __restrict__ Res, const float* __restrict__ sp,
    int N, int K, int bxi, int byi, bf16* smem)
{
    constexpr int BM = 128;
    constexpr int BK = 64;
    constexpr int WN = NW / 2;          // waves along N
    constexpr int NJ = 2;               // 2 x 16 cols per wave
    constexpr int BUF = (BM + BN) * BK; // bf16 elems per LDS buffer
    static_assert(BN == WN * 32, "wave tile is 64x32");
    static_assert(NW == 4 || NW == 8, "NW");
    static_assert(EPI == 0 || (NW == 8 && KT == 512), "EPI path: 8 waves, KT=512");

    const int tid  = threadIdx.x;
    const int wave = tid >> 6;
    const int lane = tid & 63;
    const int wm = wave / WN, wn = wave % WN;
    const size_t bm = (size_t)bxi * BM;
    const size_t bn = (size_t)byi * BN;

    f32x4 acc[4][NJ];
#pragma unroll
    for (int i = 0; i < 4; ++i)
#pragma unroll
        for (int j = 0; j < NJ; ++j)
            acc[i][j] = (f32x4){0.f, 0.f, 0.f, 0.f};

    float4 res_pre[EPI ? 8 : 1];
    const int r16 = lane >> 3;        // res/epilogue row-in-8
    const int cbb = (lane & 7) * 4;   // res/epilogue col base (float4)

    auto compute_tile = [&](const bf16* Ap, const bf16* Bp) {
#pragma unroll
        for (int kk = 0; kk < 2; ++kk) {
            const int c8 = kk * 4 + (lane >> 4);
            bf16x8 af[4], bfr[NJ];
#pragma unroll
            for (int i = 0; i < 4; ++i) {
                const int r = wm * 64 + i * 16 + (lane & 15);
                af[i] = *(const bf16x8*)&Ap[(size_t)(r * 8 + (c8 ^ (r & 7))) * 8];
            }
#pragma unroll
            for (int j = 0; j < NJ; ++j) {
                const int r = wn * 32 + j * 16 + (lane & 15);
                bfr[j] = *(const bf16x8*)&Bp[(size_t)(r * 8 + (c8 ^ (r & 7))) * 8];
            }
#pragma unroll
            for (int i = 0; i < 4; ++i)
#pragma unroll
                for (int j = 0; j < NJ; ++j)
                    acc[i][j] = __builtin_amdgcn_mfma_f32_16x16x32_bf16(af[i], bfr[j], acc[i][j], 0, 0, 0);
        }
    };

    // prologue: fill buffer 0, drain
    stage_tiles<BN, NW>(A, B, bm, bn, K, 0, smem, smem + BM * BK, wave, lane);
    __syncthreads();

    if constexpr (KT > 0) {
#pragma unroll
        for (int it = 0; it < KT / BK; ++it) {
            const int cur = it & 1;
            if (it + 1 < KT / BK) {
                bf16* nb = smem + (cur ^ 1) * BUF;
                stage_tiles<BN, NW>(A, B, bm, bn, KT, (it + 1) * BK, nb, nb + BM * BK, wave, lane);
            }
            if constexpr (EPI) {
                // one Res float4 per iteration -> HBM read overlaps K-loop
                const int i = it >> 1, rh = it & 1;
                size_t row = bm + wm * 64 + i * 16 + rh * 8 + r16;
                size_t col = bn + wn * 32 + cbb;
                res_pre[it] = *(const float4*)&Res[row * (size_t)N + col];
            }
            const bf16* Ap = smem + cur * BUF;
            compute_tile(Ap, Ap + BM * BK);
            __syncthreads();   // drains prefetch + this iter's res load
        }
    } else {
        int cur = 0;
        for (int k0 = 0; k0 < K; k0 += BK) {
            if (k0 + BK < K) {
                bf16* nb = smem + (cur ^ 1) * BUF;
                stage_tiles<BN, NW>(A, B, bm, bn, K, k0 + BK, nb, nb + BM * BK, wave, lane);
            }
            const bf16* Ap = smem + cur * BUF;
            compute_tile(Ap, Ap + BM * BK);
            __syncthreads();
            cur ^= 1;
        }
    }

    // C/D layout: col = lane&15, row = (lane>>4)*4 + reg
    const int col_l = lane & 15;
    const int row_l = (lane >> 4) * 4;
    if (EPI == 0) {
#pragma unroll
        for (int i = 0; i < 4; ++i)
#pragma unroll
            for (int j = 0; j < NJ; ++j)
#pragma unroll
                for (int r = 0; r < 4; ++r) {
                    size_t row = bm + wm * 64 + i * 16 + row_l + r;
                    size_t col = bn + wn * 32 + j * 16 + col_l;
                    Cb[row * (size_t)N + col] = __float2bfloat16(acc[i][j][r]);
                }
    } else {
        // wave-private 16x32 fp32 slice in LDS (stride 36 breaks bank aliasing);
        // no barriers: producer/consumer lanes are in the same wave.
        const float s = *sp;
        float* lds_f = (float*)smem + wave * (16 * 36);
#pragma unroll
        for (int i = 0; i < 4; ++i) {
#pragma unroll
            for (int j = 0; j < NJ; ++j)
#pragma unroll
                for (int r = 0; r < 4; ++r)
                    lds_f[(row_l + r) * 36 + j * 16 + col_l] = acc[i][j][r];
#pragma unroll
            for (int rh = 0; rh < 2; ++rh) {
                const int rr = rh * 8 + r16;
                float4 v = *(float4*)&lds_f[rr * 36 + cbb];
                size_t row = bm + wm * 64 + i * 16 + rr;
                size_t col = bn + wn * 32 + cbb;
                size_t idx = row * (size_t)N + col;
                float4 rv = res_pre[i * 2 + rh];
                float4 o;
                o.x = rv.x + s * v.x; o.y = rv.y + s * v.y;
                o.z = rv.z + s * v.z; o.w = rv.w + s * v.w;
                *(float4*)&Cf[idx] = o;
            }
        }
    }
}

// XCD-aware swizzle (T1): blocks with equal (flat & 7) land on one XCD and get
// a contiguous swz range -> all N-tiles of an M-slab share that XCD's L2.
template<int BN, int EPI, int KT, int NW>
__global__ __launch_bounds__(NW * 64) void gemm_bf16(
    const bf16* __restrict__ A, const bf16* __restrict__ B,
    bf16* __restrict__ Cb, float* __restrict__ Cf,
    const float* __restrict__ Res, const float* __restrict__ sp, int N, int K) {
    __shared__ __align__(16) bf16 smem[(128 + BN) * 64 * 2];
    const int nx = gridDim.x;
    const int flat = blockIdx.y * nx + blockIdx.x;
    const int chunk = (nx * gridDim.y) >> 3;
    const int swz = (flat & 7) * chunk + (flat >> 3);
    gemm_core<BN, EPI, KT, NW>(A, B, Cb, Cf, Res, sp, N, K,
                               swz / nx, swz % nx, smem);
}

// hs fp32->bf16 convert (8192 blocks, FIRST so the BW-bound work saturates HBM
// from dispatch 0) + R = W1*Wd, U = Wup*W2 GEMMs (256 blocks, tail), one launch.
__global__ __launch_bounds__(256) void ru_cvt(
    const bf16* __restrict__ A0, const bf16* __restrict__ B0, bf16* __restrict__ C0,
    const bf16* __restrict__ A1, const bf16* __restrict__ B1, bf16* __restrict__ C1,
    const float* __restrict__ hs, bf16* __restrict__ hsb) {
    __shared__ __align__(16) bf16 smem[(128 + 64) * 64 * 2];
    int b = blockIdx.x;
    if (b < 8192) {     // hs convert: pure BW, starts immediately
        cvt_block_2048(hs, hsb, b);
        return;
    }
    int bb = b - 8192;
    if (bb < 128)       // R = NT(W1, Wd^T): M=512,N=2048,K=512, tiles 4x32
        gemm_core<64, 0, 0, 4>(A0, B0, C0, nullptr, nullptr, nullptr, 2048, 512,
                               bb / 32, bb % 32, smem);
    else {              // U = NT(Wup, W2^T): M=2048,N=512,K=512, tiles 16x8
        bb -= 128;
        gemm_core<64, 0, 0, 4>(A1, B1, C1, nullptr, nullptr, nullptr, 512, 512,
                               bb / 8, bb % 8, smem);
    }
}

extern "C" void kernel_launch(void* const* d_in, const int* in_sizes, int n_in,
                              void* d_out, int out_size, void* d_ws, size_t ws_size,
                              hipStream_t stream) {
    // setup_inputs() order: hidden_states, w_down, w_up, w1, w2, residual_scale
    const float* hs     = (const float*)d_in[0];   // [8192, 2048]
    const float* w_down = (const float*)d_in[1];   // [512, 2048]
    const float* w_up   = (const float*)d_in[2];   // [2048, 512]
    const float* w1     = (const float*)d_in[3];   // [512, 512]
    const float* w2     = (const float*)d_in[4];   // [512, 512]
    const float* rs     = (const float*)d_in[5];   // scalar on device

    char* ws = (char*)d_ws;
    bf16* hs_b  = (bf16*)(ws + 0);          // 33,554,432  hs bf16 [8192x2048]
    bf16* x_b   = (bf16*)(ws + 33554432);   //  8,388,608  x [8192x512]
    bf16* w1_b  = (bf16*)(ws + 41943040);   //    524,288  W1 [512x512]
    bf16* wu_b  = (bf16*)(ws + 42467328);   //  2,097,152  Wup [2048x512]
    bf16* wdt_b = (bf16*)(ws + 44564480);   //  2,097,152  Wd^T [2048x512]
    bf16* w2t_b = (bf16*)(ws + 46661632);   //    524,288  W2^T [512x512]
    bf16* Rm    = (bf16*)(ws + 47185920);   //  2,097,152  R = W1*Wd [512x2048]
    bf16* Um    = (bf16*)(ws + 49283072);   //  2,097,152  U = Wup*W2 [2048x512]

    // 1) weight converts/transposes (short critical-path stage)
    prep_w<<<dim3(1920), dim3(256), 0, stream>>>(w1, w1_b, w_up, wu_b, w_down, wdt_b, w2, w2t_b);
    // 2) hs convert (first) + R,U GEMMs (tail) in one launch
    ru_cvt<<<dim3(8192 + 256), dim3(256), 0, stream>>>(w1_b, wdt_b, Rm, wu_b, w2t_b, Um, hs, hs_b);
    // 3) x = NT(hs_b, R): M=8192,N=512,K=2048. 128x128 tiles, 8 waves, dbuf.
    //    grid (4,64) = 256 blocks, XCD-swizzled.
    gemm_bf16<128, 0, 0, 8><<<dim3(4, 64), dim3(512), 0, stream>>>(hs_b, Rm, x_b, nullptr,
                                                                   nullptr, nullptr, 512, 2048);
    // 4) out = res + s*NT(x, U): M=8192,N=2048,K=512 (KT=512, 8 iters).
    //    128x128 tiles, 8 waves, dbuf, grid (16,64), XCD-swizzled,
    //    1 Res float4 per K-iter overlapped.
    gemm_bf16<128, 1, 512, 8><<<dim3(16, 64), dim3(512), 0, stream>>>(x_b, Um, nullptr, (float*)d_out,
                                                                      hs, rs, 2048, 512);
}

// Round 7
// 181.766 us; speedup vs baseline: 1.0782x; 1.0012x over previous
//
#include <hip/hip_runtime.h>
#include <hip/hip_bf16.h>
#include <stdint.h>

using bf16 = __hip_bfloat16;
typedef __attribute__((ext_vector_type(8))) short bf16x8;   // 8 bf16 raw bits (4 VGPRs)
typedef __attribute__((ext_vector_type(4))) float f32x4;

__device__ __forceinline__ void async_load16(const void* g, void* l) {
    __builtin_amdgcn_global_load_lds(
        (__attribute__((address_space(1))) const void*)g,
        (__attribute__((address_space(3))) void*)l,
        16, 0, 0);
}

// ---------------- converts ----------------
__device__ __forceinline__ void cvt_block_2048(const float* __restrict__ src,
                                               bf16* __restrict__ dst, int relblk) {
    int i = (relblk * 256 + (int)threadIdx.x) * 8;
    float4 f0 = *(const float4*)(src + i);
    float4 f1 = *(const float4*)(src + i + 4);
    union { bf16 h[8]; uint4 u; } o;
    o.h[0] = __float2bfloat16(f0.x); o.h[1] = __float2bfloat16(f0.y);
    o.h[2] = __float2bfloat16(f0.z); o.h[3] = __float2bfloat16(f0.w);
    o.h[4] = __float2bfloat16(f1.x); o.h[5] = __float2bfloat16(f1.y);
    o.h[6] = __float2bfloat16(f1.z); o.h[7] = __float2bfloat16(f1.w);
    *(uint4*)(dst + i) = o.u;
}

__global__ __launch_bounds__(256) void prep_w(
    const float* __restrict__ w1, bf16* __restrict__ w1b,
    const float* __restrict__ wup, bf16* __restrict__ wub,
    const float* __restrict__ wd, bf16* __restrict__ wdt,
    const float* __restrict__ w2, bf16* __restrict__ w2t) {
    __shared__ bf16 sh[32][33];
    int b = blockIdx.x;
    if (b < 128)       { cvt_block_2048(w1, w1b, b); return; }
    if (b < 640)       { cvt_block_2048(wup, wub, b - 128); return; }
    const float* src; bf16* dst; int R, C, tile, ntx;
    if (b < 1664) { src = wd; dst = wdt; R = 512; C = 2048; tile = b - 640; ntx = 64; }
    else          { src = w2; dst = w2t; R = 512; C = 512;  tile = b - 1664; ntx = 16; }
    const int bx = (tile % ntx) * 32, by = (tile / ntx) * 32;
    const int lx = threadIdx.x & 31;
    const int ly4 = ((int)threadIdx.x >> 5) * 4;
#pragma unroll
    for (int r = 0; r < 4; ++r)
        sh[ly4 + r][lx] = __float2bfloat16(src[(size_t)(by + ly4 + r) * C + bx + lx]);
    __syncthreads();
#pragma unroll
    for (int r = 0; r < 4; ++r)
        dst[(size_t)(bx + ly4 + r) * R + by + lx] = sh[lx][ly4 + r];
}

// ---------------- staging: global -> LDS (swizzled, linear dest) ----------------
// BK=64: chunk = 8 rows x 64 cols (1KB); unit(r,c8) = r*8 + (c8 ^ (r&7)).
// <=2-way aliasing per 16-lane ds_read_b128 phase (free, m136).
template<int BN, int NW>
__device__ __forceinline__ void stage_tiles(
    const bf16* __restrict__ A, const bf16* __restrict__ B,
    size_t bm, size_t bn, int K, int k0,
    bf16* __restrict__ As, bf16* __restrict__ Bs, int wave, int lane)
{
    const int srow = lane >> 3;
    const int scol = (lane & 7) ^ srow;
    constexpr int NCH = (128 + BN) / 8;
#pragma unroll
    for (int c = 0; c < NCH / NW; ++c) {
        const int cc = wave + c * NW;
        if (cc < 16) {
            const int rb = cc * 8;
            async_load16(A + (bm + rb + srow) * (size_t)K + k0 + scol * 8,
                         &As[rb * 64]);
        } else {
            const int rb = (cc - 16) * 8;
            async_load16(B + (bn + rb + srow) * (size_t)K + k0 + scol * 8,
                         &Bs[rb * 64]);
        }
    }
}

// ---------------- GEMM core (bf16 A and B): C[MxN] = A[MxK] * B[NxK]^T ------
// BM=128, BK=64, NW waves. Wave grid 2 x (NW/2); each wave owns a 64x32
// sub-tile -> acc[4][2]. Double-buffered LDS, prefetch-next-tile.
// EPI==1 (NW=8, KT=512): one Res float4 load per K-iter (HBM read overlaps the
// K-loop); epilogue write-only Cf = Res + s*acc via wave-private LDS transpose.
template<int BN, int EPI, int KT, int NW>
__device__ __forceinline__ void gemm_core(
    const bf16* __restrict__ A, const bf16* __restrict__ B,
    bf16* __restrict__ Cb, float* __restrict__ Cf,
    const float* __restrict__ Res, const float* __restrict__ sp,
    int N, int K, int bxi, int byi, bf16* smem)
{
    constexpr int BM = 128;
    constexpr int BK = 64;
    constexpr int WN = NW / 2;          // waves along N
    constexpr int NJ = 2;               // 2 x 16 cols per wave
    constexpr int BUF = (BM + BN) * BK; // bf16 elems per LDS buffer
    static_assert(BN == WN * 32, "wave tile is 64x32");
    static_assert(NW == 4 || NW == 8, "NW");
    static_assert(EPI == 0 || (NW == 8 && KT == 512), "EPI path: 8 waves, KT=512");

    const int tid  = threadIdx.x;
    const int wave = tid >> 6;
    const int lane = tid & 63;
    const int wm = wave / WN, wn = wave % WN;
    const size_t bm = (size_t)bxi * BM;
    const size_t bn = (size_t)byi * BN;

    f32x4 acc[4][NJ];
#pragma unroll
    for (int i = 0; i < 4; ++i)
#pragma unroll
        for (int j = 0; j < NJ; ++j)
            acc[i][j] = (f32x4){0.f, 0.f, 0.f, 0.f};

    float4 res_pre[EPI ? 8 : 1];
    const int r16 = lane >> 3;        // res/epilogue row-in-8
    const int cbb = (lane & 7) * 4;   // res/epilogue col base (float4)

    auto compute_tile = [&](const bf16* Ap, const bf16* Bp) {
#pragma unroll
        for (int kk = 0; kk < 2; ++kk) {
            const int c8 = kk * 4 + (lane >> 4);
            bf16x8 af[4], bfr[NJ];
#pragma unroll
            for (int i = 0; i < 4; ++i) {
                const int r = wm * 64 + i * 16 + (lane & 15);
                af[i] = *(const bf16x8*)&Ap[(size_t)(r * 8 + (c8 ^ (r & 7))) * 8];
            }
#pragma unroll
            for (int j = 0; j < NJ; ++j) {
                const int r = wn * 32 + j * 16 + (lane & 15);
                bfr[j] = *(const bf16x8*)&Bp[(size_t)(r * 8 + (c8 ^ (r & 7))) * 8];
            }
#pragma unroll
            for (int i = 0; i < 4; ++i)
#pragma unroll
                for (int j = 0; j < NJ; ++j)
                    acc[i][j] = __builtin_amdgcn_mfma_f32_16x16x32_bf16(af[i], bfr[j], acc[i][j], 0, 0, 0);
        }
    };

    // prologue: fill buffer 0, drain
    stage_tiles<BN, NW>(A, B, bm, bn, K, 0, smem, smem + BM * BK, wave, lane);
    __syncthreads();

    if constexpr (KT > 0) {
#pragma unroll
        for (int it = 0; it < KT / BK; ++it) {
            const int cur = it & 1;
            if (it + 1 < KT / BK) {
                bf16* nb = smem + (cur ^ 1) * BUF;
                stage_tiles<BN, NW>(A, B, bm, bn, KT, (it + 1) * BK, nb, nb + BM * BK, wave, lane);
            }
            if constexpr (EPI) {
                // one Res float4 per iteration -> HBM read overlaps K-loop
                const int i = it >> 1, rh = it & 1;
                size_t row = bm + wm * 64 + i * 16 + rh * 8 + r16;
                size_t col = bn + wn * 32 + cbb;
                res_pre[it] = *(const float4*)&Res[row * (size_t)N + col];
            }
            const bf16* Ap = smem + cur * BUF;
            compute_tile(Ap, Ap + BM * BK);
            __syncthreads();   // drains prefetch + this iter's res load
        }
    } else {
        int cur = 0;
        for (int k0 = 0; k0 < K; k0 += BK) {
            if (k0 + BK < K) {
                bf16* nb = smem + (cur ^ 1) * BUF;
                stage_tiles<BN, NW>(A, B, bm, bn, K, k0 + BK, nb, nb + BM * BK, wave, lane);
            }
            const bf16* Ap = smem + cur * BUF;
            compute_tile(Ap, Ap + BM * BK);
            __syncthreads();
            cur ^= 1;
        }
    }

    // C/D layout: col = lane&15, row = (lane>>4)*4 + reg
    const int col_l = lane & 15;
    const int row_l = (lane >> 4) * 4;
    if (EPI == 0) {
#pragma unroll
        for (int i = 0; i < 4; ++i)
#pragma unroll
            for (int j = 0; j < NJ; ++j)
#pragma unroll
                for (int r = 0; r < 4; ++r) {
                    size_t row = bm + wm * 64 + i * 16 + row_l + r;
                    size_t col = bn + wn * 32 + j * 16 + col_l;
                    Cb[row * (size_t)N + col] = __float2bfloat16(acc[i][j][r]);
                }
    } else {
        // wave-private 16x32 fp32 slice in LDS (stride 36 breaks bank aliasing);
        // no barriers: producer/consumer lanes are in the same wave.
        const float s = *sp;
        float* lds_f = (float*)smem + wave * (16 * 36);
#pragma unroll
        for (int i = 0; i < 4; ++i) {
#pragma unroll
            for (int j = 0; j < NJ; ++j)
#pragma unroll
                for (int r = 0; r < 4; ++r)
                    lds_f[(row_l + r) * 36 + j * 16 + col_l] = acc[i][j][r];
#pragma unroll
            for (int rh = 0; rh < 2; ++rh) {
                const int rr = rh * 8 + r16;
                float4 v = *(float4*)&lds_f[rr * 36 + cbb];
                size_t row = bm + wm * 64 + i * 16 + rr;
                size_t col = bn + wn * 32 + cbb;
                size_t idx = row * (size_t)N + col;
                float4 rv = res_pre[i * 2 + rh];
                float4 o;
                o.x = rv.x + s * v.x; o.y = rv.y + s * v.y;
                o.z = rv.z + s * v.z; o.w = rv.w + s * v.w;
                *(float4*)&Cf[idx] = o;
            }
        }
    }
}

// XCD-aware swizzle (T1): blocks with equal (flat & 7) land on one XCD and get
// a contiguous swz range -> all N-tiles of an M-slab share that XCD's L2.
template<int BN, int EPI, int KT, int NW>
__global__ __launch_bounds__(NW * 64) void gemm_bf16(
    const bf16* __restrict__ A, const bf16* __restrict__ B,
    bf16* __restrict__ Cb, float* __restrict__ Cf,
    const float* __restrict__ Res, const float* __restrict__ sp, int N, int K) {
    __shared__ __align__(16) bf16 smem[(128 + BN) * 64 * 2];
    const int nx = gridDim.x;
    const int flat = blockIdx.y * nx + blockIdx.x;
    const int chunk = (nx * gridDim.y) >> 3;
    const int swz = (flat & 7) * chunk + (flat >> 3);
    gemm_core<BN, EPI, KT, NW>(A, B, Cb, Cf, Res, sp, N, K,
                               swz / nx, swz % nx, smem);
}

// ---------------- x_gemm3: x = NT(hs_b, R), 3-buffer counted-vmcnt (T4) -----
// M=8192, N=512, K=2048. BM=BN=128, BK=64, 8 waves (wave grid 2x4, 64x32
// tiles). Three LDS buffers; stage t+2 stays IN FLIGHT across two compute
// phases. Per iter: wait own stage-t loads only (vmcnt(4), never 0 mid-loop)
// -> raw s_barrier -> issue stage t+2 -> compute buf t.
// Race-safety: (1) vmcnt(4)+barrier => all waves' stage-t writes landed before
// any compute-t read; (2) stage t+2 (-> buf (t-1)%3) issues after the iter-t
// barrier, and every wave's iter-(t-1) ds_reads completed before that barrier
// (each read is consumed by an MFMA preceding it; HW waits lgkmcnt before the
// consuming MFMA); (3) mod-3 buffers keep writer/reader sets disjoint.
__global__ __launch_bounds__(512) void x_gemm3(
    const bf16* __restrict__ A, const bf16* __restrict__ B,
    bf16* __restrict__ Cb, int N, int K)
{
    constexpr int BM = 128, BN = 128, BK = 64;
    constexpr int BUF = (BM + BN) * BK;            // 16384 bf16 = 32 KB
    __shared__ __align__(16) bf16 smem[BUF * 3];   // 96 KB

    const int nx = gridDim.x;
    const int flat = blockIdx.y * nx + blockIdx.x;
    const int chunk = (nx * gridDim.y) >> 3;
    const int swz = (flat & 7) * chunk + (flat >> 3);
    const int bxi = swz / nx, byi = swz % nx;
    const size_t bm = (size_t)bxi * BM;
    const size_t bn = (size_t)byi * BN;

    const int tid = threadIdx.x, wave = tid >> 6, lane = tid & 63;
    const int wm = wave >> 2, wn = wave & 3;       // 2 x 4 wave grid

    f32x4 acc[4][2];
#pragma unroll
    for (int i = 0; i < 4; ++i)
#pragma unroll
        for (int j = 0; j < 2; ++j)
            acc[i][j] = (f32x4){0.f, 0.f, 0.f, 0.f};

    auto stage = [&](int b, int k0) {   // 4 async_load16 per lane -> vmcnt +4
        bf16* base = smem + b * BUF;
        stage_tiles<BN, 8>(A, B, bm, bn, K, k0, base, base + BM * BK, wave, lane);
    };
    auto compute = [&](int b) {
        const bf16* Ap = smem + b * BUF;
        const bf16* Bp = Ap + BM * BK;
#pragma unroll
        for (int kk = 0; kk < 2; ++kk) {
            const int c8 = kk * 4 + (lane >> 4);
            bf16x8 af[4], bfr[2];
#pragma unroll
            for (int i = 0; i < 4; ++i) {
                const int r = wm * 64 + i * 16 + (lane & 15);
                af[i] = *(const bf16x8*)&Ap[(size_t)(r * 8 + (c8 ^ (r & 7))) * 8];
            }
#pragma unroll
            for (int j = 0; j < 2; ++j) {
                const int r = wn * 32 + j * 16 + (lane & 15);
                bfr[j] = *(const bf16x8*)&Bp[(size_t)(r * 8 + (c8 ^ (r & 7))) * 8];
            }
#pragma unroll
            for (int i = 0; i < 4; ++i)
#pragma unroll
                for (int j = 0; j < 2; ++j)
                    acc[i][j] = __builtin_amdgcn_mfma_f32_16x16x32_bf16(af[i], bfr[j], acc[i][j], 0, 0, 0);
        }
    };

    const int NT = K / BK;                         // 32
    stage(0, 0);
    stage(1, BK);                                  // 8 loads in flight per lane

    for (int t = 0; t < NT; ++t) {
        if (t + 1 < NT) {
            asm volatile("s_waitcnt vmcnt(4)" ::: "memory");   // stage t done
        } else {
            asm volatile("s_waitcnt vmcnt(0)" ::: "memory");   // last tile
        }
        __builtin_amdgcn_sched_barrier(0);
        __builtin_amdgcn_s_barrier();              // all waves' stage-t landed
        __builtin_amdgcn_sched_barrier(0);
        if (t + 2 < NT) stage((t + 2) % 3, (t + 2) * BK);      // issue early
        compute(t % 3);
    }

    const int col_l = lane & 15;
    const int row_l = (lane >> 4) * 4;
#pragma unroll
    for (int i = 0; i < 4; ++i)
#pragma unroll
        for (int j = 0; j < 2; ++j)
#pragma unroll
            for (int r = 0; r < 4; ++r) {
                size_t row = bm + wm * 64 + i * 16 + row_l + r;
                size_t col = bn + wn * 32 + j * 16 + col_l;
                Cb[row * (size_t)N + col] = __float2bfloat16(acc[i][j][r]);
            }
}

// hs fp32->bf16 convert (8192 blocks, FIRST so the BW-bound work saturates HBM
// from dispatch 0) + R = W1*Wd, U = Wup*W2 GEMMs (256 blocks, tail), one launch.
__global__ __launch_bounds__(256) void ru_cvt(
    const bf16* __restrict__ A0, const bf16* __restrict__ B0, bf16* __restrict__ C0,
    const bf16* __restrict__ A1, const bf16* __restrict__ B1, bf16* __restrict__ C1,
    const float* __restrict__ hs, bf16* __restrict__ hsb) {
    __shared__ __align__(16) bf16 smem[(128 + 64) * 64 * 2];
    int b = blockIdx.x;
    if (b < 8192) {     // hs convert: pure BW, starts immediately
        cvt_block_2048(hs, hsb, b);
        return;
    }
    int bb = b - 8192;
    if (bb < 128)       // R = NT(W1, Wd^T): M=512,N=2048,K=512, tiles 4x32
        gemm_core<64, 0, 0, 4>(A0, B0, C0, nullptr, nullptr, nullptr, 2048, 512,
                               bb / 32, bb % 32, smem);
    else {              // U = NT(Wup, W2^T): M=2048,N=512,K=512, tiles 16x8
        bb -= 128;
        gemm_core<64, 0, 0, 4>(A1, B1, C1, nullptr, nullptr, nullptr, 512, 512,
                               bb / 8, bb % 8, smem);
    }
}

extern "C" void kernel_launch(void* const* d_in, const int* in_sizes, int n_in,
                              void* d_out, int out_size, void* d_ws, size_t ws_size,
                              hipStream_t stream) {
    // setup_inputs() order: hidden_states, w_down, w_up, w1, w2, residual_scale
    const float* hs     = (const float*)d_in[0];   // [8192, 2048]
    const float* w_down = (const float*)d_in[1];   // [512, 2048]
    const float* w_up   = (const float*)d_in[2];   // [2048, 512]
    const float* w1     = (const float*)d_in[3];   // [512, 512]
    const float* w2     = (const float*)d_in[4];   // [512, 512]
    const float* rs     = (const float*)d_in[5];   // scalar on device

    char* ws = (char*)d_ws;
    bf16* hs_b  = (bf16*)(ws + 0);          // 33,554,432  hs bf16 [8192x2048]
    bf16* x_b   = (bf16*)(ws + 33554432);   //  8,388,608  x [8192x512]
    bf16* w1_b  = (bf16*)(ws + 41943040);   //    524,288  W1 [512x512]
    bf16* wu_b  = (bf16*)(ws + 42467328);   //  2,097,152  Wup [2048x512]
    bf16* wdt_b = (bf16*)(ws + 44564480);   //  2,097,152  Wd^T [2048x512]
    bf16* w2t_b = (bf16*)(ws + 46661632);   //    524,288  W2^T [512x512]
    bf16* Rm    = (bf16*)(ws + 47185920);   //  2,097,152  R = W1*Wd [512x2048]
    bf16* Um    = (bf16*)(ws + 49283072);   //  2,097,152  U = Wup*W2 [2048x512]

    // 1) weight converts/transposes (short critical-path stage)
    prep_w<<<dim3(1920), dim3(256), 0, stream>>>(w1, w1_b, w_up, wu_b, w_down, wdt_b, w2, w2t_b);
    // 2) hs convert (first) + R,U GEMMs (tail) in one launch
    ru_cvt<<<dim3(8192 + 256), dim3(256), 0, stream>>>(w1_b, wdt_b, Rm, wu_b, w2t_b, Um, hs, hs_b);
    // 3) x = NT(hs_b, R): M=8192,N=512,K=2048. 3-buffer counted-vmcnt pipeline,
    //    8 waves, 96 KB LDS, grid (4,64) = 256 blocks, XCD-swizzled.
    x_gemm3<<<dim3(4, 64), dim3(512), 0, stream>>>(hs_b, Rm, x_b, 512, 2048);
    // 4) out = res + s*NT(x, U): M=8192,N=2048,K=512 (KT=512, 8 iters).
    //    128x128 tiles, 8 waves, dbuf, grid (16,64), XCD-swizzled,
    //    1 Res float4 per K-iter overlapped.
    gemm_bf16<128, 1, 512, 8><<<dim3(16, 64), dim3(512), 0, stream>>>(x_b, Um, nullptr, (float*)d_out,
                                                                      hs, rs, 2048, 512);
}